// Round 3
// baseline (14201.584 us; speedup 1.0000x reference)
//
#include <hip/hip_runtime.h>
#include <hip/hip_bf16.h>
#include <stdint.h>
#include <math.h>

typedef __bf16 bf16;
typedef __bf16 bf16x8 __attribute__((ext_vector_type(8)));
typedef float f32x4 __attribute__((ext_vector_type(4)));

// B=8, H=W=128, dim=256, mid=128. fp32 I/O; internal hi/lo bf16 pairs.
// conv = 3-term bf16 (WhAh + WhAl + WlAh). A (weights) loaded global->reg per
// tap from a FRAGMENT-MAJOR repack [2*tap+s][ci_chunk][co][32ci] (one 1KB
// coalesced wave-load per fragment, L2-resident); B staged once per K-chunk in
// an XOR-swizzled LDS slab (conflict-free ds_read_b128); no per-tap barriers.
// NW=8 (512 thr) blocks produce 256 cout each: halves staging work + doubles
// resident waves (24/CU) for the Cout=256 convs. NW=4 for Cout=128 convs.

// ---------------- x: NCHW fp32 -> NHWC hi/lo bf16 (512 ch)
__global__ void k_x_split(const float* __restrict__ in, bf16* __restrict__ out) {
  __shared__ float t[32][33];
  const int b = blockIdx.z;
  const int p0 = blockIdx.x << 5, c0 = blockIdx.y << 5;
  const int tx = threadIdx.x, ty = threadIdx.y;  // block (32,8)
  const float* ib = in + (size_t)b * 256 * 16384;
  bf16* ob = out + (size_t)b * 16384 * 512;
#pragma unroll
  for (int k = 0; k < 32; k += 8)
    t[ty + k][tx] = ib[(size_t)(c0 + ty + k) * 16384 + p0 + tx];
  __syncthreads();
#pragma unroll
  for (int k = 0; k < 32; k += 8) {
    float v = t[tx][ty + k];
    bf16 hv = (bf16)v;
    bf16 lv = (bf16)(v - (float)hv);
    ob[(size_t)(p0 + ty + k) * 512 + c0 + tx] = hv;
    ob[(size_t)(p0 + ty + k) * 512 + 256 + c0 + tx] = lv;
  }
}

// ---------------- weight repack fp32 OIHW -> bf16 [2*tap+s][ci_chunk][co][32ci]
// (s=0 Wh, s=1 Wl). Per-(seg,tap) block is chunk-major so a wave's MFMA A
// fragment (16 co x 32 ci) is 1KB contiguous.
__global__ void k_repack2(const float* __restrict__ src, bf16* __restrict__ dst,
                          int Cout, int Cin, int taps, int coutTotal, int coff) {
  int tid = blockIdx.x * 256 + threadIdx.x;
  int total = Cout * Cin * taps;
  if (tid >= total) return;
  int t = tid % taps;
  int rest = tid / taps;
  int ci = rest % Cin;
  int co = rest / Cin;
  float w = src[tid];
  bf16 wh = (bf16)w;
  bf16 wl = (bf16)(w - (float)wh);
  int nchunk = Cin >> 5;
  size_t segsz = (size_t)coutTotal * Cin;  // = nchunk*coutTotal*32
  size_t base = (((size_t)(2 * t) * nchunk + (ci >> 5)) * coutTotal + coff + co) * 32
                + (ci & 31);
  dst[base] = wh;
  dst[base + segsz] = wl;
}

// ---------------- BN coefficients
__global__ void k_bncoef(const float* __restrict__ g, const float* __restrict__ b,
                         const float* __restrict__ m, const float* __restrict__ v,
                         float* __restrict__ sc, float* __restrict__ sh, int n) {
  int c = blockIdx.x * 256 + threadIdx.x;
  if (c >= n) return;
  float s = g[c] * (1.0f / sqrtf(v[c] + 1e-5f));
  sc[c] = s;
  sh[c] = b[c] - m[c] * s;
}

// ---------------- implicit-GEMM conv, A from global (fragment-major), swizzled B slab
// in: hi/lo act tensor (hi at +0, lo at +Cin within rowStride-ch rows).
// out_mode: 0 = hi/lo bf16 NHWC (2*Cout ch), 1 = fp32 NHWC compact,
// 2 = fp32 NCHW. addbuf: hi/lo, stride 2*Cout. Block covers NW*32 cout x 128 pos.
template <int NTAPS, int NW>
__global__ __launch_bounds__(NW * 64, (NW == 8) ? 6 : 3)
void k_conv(const bf16* __restrict__ in, int Cin, int rowStride,
            const bf16* __restrict__ Wr, int Cout,
            const float* __restrict__ scale, const float* __restrict__ shift,
            const bf16* __restrict__ addbuf, int relu,
            int out_mode, void* __restrict__ out) {
  constexpr int R = (NTAPS == 9) ? 3 : 1;
  constexpr int NT = NW * 64;
  __shared__ bf16 b_slab[2 * R * 130 * 32];  // plane = hl*R + r; pos -1..128 at +1
  const int bx = blockIdx.x;
  const int bb = bx & 7, h = (bx >> 3) & 127;   // XCD swizzle: batch == XCD
  const int row = bb * 128 + h;
  const int co_block = blockIdx.y * (NW * 32);
  const int tid = threadIdx.x;
  const int lane = tid & 63, wave = tid >> 6;
  const int wm = (wave >> 1) << 6, wn = (wave & 1) << 6;
  const int quad = lane >> 4, l15 = lane & 15;
  const int nchunk = Cin >> 5;
  const size_t segsz = (size_t)Cout * Cin;  // seg stride in repacked weights

  f32x4 acc[4][4];
#pragma unroll
  for (int i = 0; i < 4; ++i)
#pragma unroll
    for (int j = 0; j < 4; ++j)
#pragma unroll
      for (int r = 0; r < 4; ++r) acc[i][j][r] = 0.0f;

  constexpr int nunits = 2 * R * 130;

  for (int cb = 0; cb < Cin; cb += 32) {
    // ---- stage B slab (once per chunk): 2(hl) x R rows x 130 pos x 32 ch
    // XOR-swizzled: granule s (8ch) of row p stored at slot s ^ ((p>>1)&3)
    for (int u = tid; u < nunits; u += NT) {
      int plane = u / 130, p = u - plane * 130;
      int hl, r;
      if (R == 3) { hl = plane >= 3; r = plane - (hl ? 3 : 0); }
      else        { hl = plane; r = 0; }
      int hi = h + r - (R == 3 ? 1 : 0);
      int wi = p - 1;
      uint4 v0, v1, v2, v3;
      v0.x = v0.y = v0.z = v0.w = 0u; v1 = v0; v2 = v0; v3 = v0;
      if ((unsigned)hi < 128u && (unsigned)wi < 128u) {
        const bf16* s = in + (size_t)((bb * 128 + hi) * 128 + wi) * rowStride
                        + (size_t)hl * Cin + cb;
        v0 = *(const uint4*)s;
        v1 = *(const uint4*)(s + 8);
        v2 = *(const uint4*)(s + 16);
        v3 = *(const uint4*)(s + 24);
      }
      bf16* d = &b_slab[(size_t)(plane * 130 + p) * 32];
      const int sw = (p >> 1) & 3;
      *(uint4*)(d + ((0 ^ sw) << 3)) = v0;
      *(uint4*)(d + ((1 ^ sw) << 3)) = v1;
      *(uint4*)(d + ((2 ^ sw) << 3)) = v2;
      *(uint4*)(d + ((3 ^ sw) << 3)) = v3;
    }
    __syncthreads();
#pragma unroll
    for (int tap = 0; tap < NTAPS; ++tap) {
      const int rr = (R == 3) ? (tap / 3) : 0;        // slab row
      const int wc = (R == 3) ? (tap % 3) : 1;        // dw+1 column offset
      const int bH = rr * 130;
      const int bL = (R + rr) * 130;
      const int p0 = wn + l15 + wc;                   // j=0 position (j adds 16)
      const int sw8 = (((p0 >> 1) & 3) ^ quad) << 3;  // invariant across j
      // ---- A fragments straight from L2; fragment-major layout:
      // lane addr = l15*64B + quad*16B -> one coalesced 1KB load per fragment
      const bf16* Ah = Wr + (((size_t)(2 * tap) * nchunk + (cb >> 5)) * Cout
                             + co_block + wm + l15) * 32 + quad * 8;
      const bf16* Al = Ah + segsz;
      bf16x8 afH[4], afL[4], bfH[4], bfL[4];
#pragma unroll
      for (int i = 0; i < 4; ++i) {
        afH[i] = *(const bf16x8*)(Ah + (size_t)i * 16 * 32);
        afL[i] = *(const bf16x8*)(Al + (size_t)i * 16 * 32);
      }
#pragma unroll
      for (int j = 0; j < 4; ++j) {
        const int p_idx = p0 + j * 16;
        bfH[j] = *(const bf16x8*)&b_slab[(size_t)(bH + p_idx) * 32 + sw8];
        bfL[j] = *(const bf16x8*)&b_slab[(size_t)(bL + p_idx) * 32 + sw8];
      }
#pragma unroll
      for (int i = 0; i < 4; ++i)
#pragma unroll
        for (int j = 0; j < 4; ++j) {
          acc[i][j] = __builtin_amdgcn_mfma_f32_16x16x32_bf16(afH[i], bfH[j], acc[i][j], 0, 0, 0);
          acc[i][j] = __builtin_amdgcn_mfma_f32_16x16x32_bf16(afH[i], bfL[j], acc[i][j], 0, 0, 0);
          acc[i][j] = __builtin_amdgcn_mfma_f32_16x16x32_bf16(afL[i], bfH[j], acc[i][j], 0, 0, 0);
        }
    }
    __syncthreads();  // slab reads done before next chunk's restage
  }

  // epilogue: D row(m=cout)=quad*4+reg, col(n=pos)=lane&15
#pragma unroll
  for (int i = 0; i < 4; ++i) {
    const int co = co_block + wm + i * 16 + (quad << 2);
#pragma unroll
    for (int j = 0; j < 4; ++j) {
      const int pos = wn + j * 16 + l15;
      float v[4];
#pragma unroll
      for (int r = 0; r < 4; ++r) v[r] = acc[i][j][r];
      if (scale) {
#pragma unroll
        for (int r = 0; r < 4; ++r) v[r] = v[r] * scale[co + r] + shift[co + r];
      }
      if (addbuf) {
        const bf16* ah = addbuf + (size_t)(row * 128 + pos) * (2 * Cout) + co;
        const bf16* al = ah + Cout;
#pragma unroll
        for (int r = 0; r < 4; ++r) v[r] += (float)ah[r] + (float)al[r];
      }
      if (relu) {
#pragma unroll
        for (int r = 0; r < 4; ++r) v[r] = fmaxf(v[r], 0.0f);
      }
      if (out_mode == 0) {
        bf16* ob = (bf16*)out;
        union { bf16 hv[4]; uint2 u; } ph, pl;
#pragma unroll
        for (int r = 0; r < 4; ++r) {
          ph.hv[r] = (bf16)v[r];
          pl.hv[r] = (bf16)(v[r] - (float)ph.hv[r]);
        }
        const size_t base = (size_t)(row * 128 + pos) * (2 * Cout);
        *(uint2*)&ob[base + co] = ph.u;
        *(uint2*)&ob[base + Cout + co] = pl.u;
      } else if (out_mode == 1) {
        float* of = (float*)out;
        float4 pk = make_float4(v[0], v[1], v[2], v[3]);
        *(float4*)&of[(size_t)(row * 128 + pos) * Cout + co] = pk;
      } else {
        float* of = (float*)out;
#pragma unroll
        for (int r = 0; r < 4; ++r)
          of[((size_t)(bb * Cout + co + r) * 128 + h) * 128 + pos] = v[r];
      }
    }
  }
}

// ---------------- pools (fp32 reconstruct, scan, re-split), in-place
// y: 512ch rows [lookH 0:128 | pH 128:256 | lookL 256:384 | pL 384:512]
__global__ void k_pool_s1(bf16* __restrict__ y) {  // left_pool: scan w
  int tid = blockIdx.x * 256 + threadIdx.x;
  int c = tid & 127, h = (tid >> 7) & 127, b = tid >> 14;
  bf16* base = y + (size_t)((b * 128 + h) * 128) * 512;
  float run = -INFINITY;
  for (int w = 127; w >= 0; --w) {
    bf16* p = base + (size_t)w * 512;
    float look = (float)p[c] + (float)p[256 + c];
    float padd = (float)p[128 + c] + (float)p[384 + c];
    run = fmaxf(run, look);
    float sum = run + padd;
    bf16 hv = (bf16)sum;
    p[c] = hv;
    p[128 + c] = (bf16)(sum - (float)hv);
  }
}
__global__ void k_pool_s2(bf16* __restrict__ y) {  // top_pool: scan h
  int tid = blockIdx.x * 256 + threadIdx.x;
  int c = tid & 127, w = (tid >> 7) & 127, b = tid >> 14;
  bf16* base = y + ((size_t)b * 16384 + w) * 512;
  float run = -INFINITY;
  for (int hh = 127; hh >= 0; --hh) {
    bf16* p = base + (size_t)hh * 65536;
    float look = (float)p[c] + (float)p[256 + c];
    float padd = (float)p[128 + c] + (float)p[384 + c];
    run = fmaxf(run, look);
    float sum = run + padd;
    bf16 hv = (bf16)sum;
    p[c] = hv;
    p[128 + c] = (bf16)(sum - (float)hv);
  }
}
__global__ void k_tpool_f(float* __restrict__ buf) {  // in-place top_pool fp32
  int tid = blockIdx.x * 256 + threadIdx.x;
  int c = tid & 127, w = (tid >> 7) & 127, b = tid >> 14;
  float* p = buf + ((size_t)b * 16384 + w) * 128 + c;
  float run = -INFINITY;
  for (int hh = 127; hh >= 0; --hh) {
    run = fmaxf(run, p[(size_t)hh * 16384]);
    p[(size_t)hh * 16384] = run;
  }
}
__global__ void k_lpool_add_f(const float* __restrict__ in, const float* __restrict__ addb,
                              bf16* __restrict__ out) {
  int tid = blockIdx.x * 256 + threadIdx.x;
  int c = tid & 127, h = (tid >> 7) & 127, b = tid >> 14;
  const float* p = in + (size_t)((b * 128 + h) * 128) * 128 + c;
  const float* a = addb + (size_t)((b * 128 + h) * 128) * 128 + c;
  bf16* o = out + (size_t)((b * 128 + h) * 128) * 256;
  float run = -INFINITY;
  for (int w = 127; w >= 0; --w) {
    run = fmaxf(run, p[(size_t)w * 128]);
    float sum = run + a[(size_t)w * 128];
    bf16 hv = (bf16)sum;
    o[(size_t)w * 256 + c] = hv;
    o[(size_t)w * 256 + 128 + c] = (bf16)(sum - (float)hv);
  }
}

extern "C" void kernel_launch(void* const* d_in, const int* in_sizes, int n_in,
                              void* d_out, int out_size, void* d_ws, size_t ws_size,
                              hipStream_t stream) {
  (void)in_sizes; (void)n_in; (void)out_size; (void)ws_size;
#define INF(i) ((const float*)d_in[i])
  char* ws = (char*)d_ws;
  const size_t MB = 1 << 20;
  // weights [0, ~9.75MB): [2*tap+s][ci_chunk][co][32]
  bf16* wrA  = (bf16*)(ws + 0);          // 18*256*256
  bf16* wrB  = (bf16*)(ws + 2359296);
  bf16* wrp1 = (bf16*)(ws + 4718592);    // 18*128*128
  bf16* wrp2 = (bf16*)(ws + 5308416);
  bf16* wrpc = (bf16*)(ws + 5898240);    // 18*256*128
  bf16* wrc1 = (bf16*)(ws + 7077888);    // 2*256*256
  bf16* wrc2 = (bf16*)(ws + 7340032);    // 18*256*256
  float* scA  = (float*)(ws + 9699328);
  float* shA  = (float*)(ws + 9703424);
  float* scB  = (float*)(ws + 9707520);
  float* shB  = (float*)(ws + 9711616);
  float* scp  = (float*)(ws + 9715712);
  float* shp  = (float*)(ws + 9719808);
  float* scb  = (float*)(ws + 9723904);
  float* shb  = (float*)(ws + 9728000);
  float* scc2 = (float*)(ws + 9732096);
  float* shc2 = (float*)(ws + 9736192);
  // activations (ws use <= 330 MB; d_out doubles as 128 MB scratch)
  bf16*  x_hl  = (bf16*)(ws + 10 * MB);    // 128 MB, live thru step 8
  bf16*  bnrel = (bf16*)(ws + 138 * MB);   // 128 MB: bn1 -> relu1 in-place
  float* p1lk  = (float*)(ws + 266 * MB);  // 64 MB fp32
  float* p2lk  = (float*)(ws + 10 * MB);   // 64 MB fp32 over dead x_hl
  bf16*  psum  = (bf16*)(ws + 74 * MB);    // 64 MB hi/lo compact 256ch
  bf16*  yscr  = (bf16*)d_out;             // 128 MB scratch: yA/s1 then yB/s2

  // 1) x -> NHWC hi/lo
  k_x_split<<<dim3(512, 8, 8), dim3(32, 8), 0, stream>>>(INF(0), x_hl);

  // 2) weight repacks (Wh/Wl segments)
  k_repack2<<<1152, 256, 0, stream>>>(INF(1),  wrA,  128, 256, 9, 256, 0);
  k_repack2<<<1152, 256, 0, stream>>>(INF(6),  wrA,  128, 256, 9, 256, 128);
  k_repack2<<<1152, 256, 0, stream>>>(INF(11), wrB,  128, 256, 9, 256, 0);
  k_repack2<<<1152, 256, 0, stream>>>(INF(16), wrB,  128, 256, 9, 256, 128);
  k_repack2<<<576,  256, 0, stream>>>(INF(21), wrp1, 128, 128, 9, 128, 0);
  k_repack2<<<576,  256, 0, stream>>>(INF(22), wrp2, 128, 128, 9, 128, 0);
  k_repack2<<<1152, 256, 0, stream>>>(INF(23), wrpc, 256, 128, 9, 256, 0);
  k_repack2<<<256,  256, 0, stream>>>(INF(28), wrc1, 256, 256, 1, 256, 0);
  k_repack2<<<2304, 256, 0, stream>>>(INF(33), wrc2, 256, 256, 9, 256, 0);

  // 3) BN coefficients
  k_bncoef<<<1, 256, 0, stream>>>(INF(2),  INF(3),  INF(4),  INF(5),  scA,       shA,       128);
  k_bncoef<<<1, 256, 0, stream>>>(INF(7),  INF(8),  INF(9),  INF(10), scA + 128, shA + 128, 128);
  k_bncoef<<<1, 256, 0, stream>>>(INF(12), INF(13), INF(14), INF(15), scB,       shB,       128);
  k_bncoef<<<1, 256, 0, stream>>>(INF(17), INF(18), INF(19), INF(20), scB + 128, shB + 128, 128);
  k_bncoef<<<1, 256, 0, stream>>>(INF(24), INF(25), INF(26), INF(27), scp, shp, 256);
  k_bncoef<<<1, 256, 0, stream>>>(INF(29), INF(30), INF(31), INF(32), scb, shb, 256);
  k_bncoef<<<1, 256, 0, stream>>>(INF(34), INF(35), INF(36), INF(37), scc2, shc2, 256);

  // 4) bn1 = BN(conv1x1(x)) -> bnrel (hi/lo)
  k_conv<1, 8><<<dim3(1024, 1), 512, 0, stream>>>(x_hl, 256, 512, wrc1, 256, scb, shb, nullptr, 0, 0, bnrel);
  // 5) yA = [look_conv1 | p1_conv1] (BN+ReLU) -> d_out scratch
  k_conv<9, 8><<<dim3(1024, 1), 512, 0, stream>>>(x_hl, 256, 512, wrA, 256, scA, shA, nullptr, 1, 0, yscr);
  // 6) s1 = left_pool(look1) + p1_conv1 (in-place, ch [0:256))
  k_pool_s1<<<512, 256, 0, stream>>>(yscr);
  // 7) p1_look = conv(s1, p1lc) -> fp32
  k_conv<9, 4><<<dim3(1024, 1), 256, 0, stream>>>(yscr, 128, 512, wrp1, 128, nullptr, nullptr, nullptr, 0, 1, p1lk);
  // 8) yB = [look_conv2 | p2_conv1] -> d_out scratch (x dead after)
  k_conv<9, 8><<<dim3(1024, 1), 512, 0, stream>>>(x_hl, 256, 512, wrB, 256, scB, shB, nullptr, 1, 0, yscr);
  // 9) s2 = top_pool(look2) + p2_conv1 (in-place)
  k_pool_s2<<<512, 256, 0, stream>>>(yscr);
  // 10) p2_look = conv(s2, p2lc) -> fp32 (over dead x_hl)
  k_conv<9, 4><<<dim3(1024, 1), 256, 0, stream>>>(yscr, 128, 512, wrp2, 128, nullptr, nullptr, nullptr, 0, 1, p2lk);
  // 11) ptmp = top_pool(p1_look) in-place
  k_tpool_f<<<512, 256, 0, stream>>>(p1lk);
  // 12) psum = left_pool(p2_look) + ptmp -> hi/lo compact
  k_lpool_add_f<<<512, 256, 0, stream>>>(p2lk, p1lk, psum);
  // 13) relu1 = relu(BN(conv(psum, pconv1)) + bn1) in-place over bn1
  k_conv<9, 8><<<dim3(1024, 1), 512, 0, stream>>>(psum, 128, 256, wrpc, 256, scp, shp, bnrel, 1, 0, bnrel);
  // 14) out = relu(BN(conv(relu1, c2))) -> NCHW fp32 d_out
  k_conv<9, 8><<<dim3(1024, 1), 512, 0, stream>>>(bnrel, 256, 512, wrc2, 256, scc2, shc2, nullptr, 1, 2, (float*)d_out);
#undef INF
}

// Round 4
// 3928.919 us; speedup vs baseline: 3.6146x; 3.6146x over previous
//
#include <hip/hip_runtime.h>
#include <hip/hip_bf16.h>
#include <stdint.h>
#include <math.h>

typedef __bf16 bf16;
typedef __bf16 bf16x8 __attribute__((ext_vector_type(8)));
typedef float f32x4 __attribute__((ext_vector_type(4)));

// B=8, H=W=128, dim=256, mid=128. fp32 I/O; internal hi/lo bf16 pairs.
// conv = 3-term bf16 (WhAh + WhAl + WlAh). A (weights) loaded global->reg per
// tap from a FRAGMENT-MAJOR repack [2*tap+s][ci_chunk][co][32ci] (one 1KB
// coalesced wave-load per fragment, L2-resident); B staged once per K-chunk in
// an XOR-swizzled LDS slab (conflict-free ds_read_b128); no per-tap barriers.
// NW=8 (512 thr) blocks produce 256 cout each: halves staging work + 24
// waves/CU. launch_bounds 2nd arg = 3 (NOT 6: that capped VGPR at 40 and
// spilled acc -> 16.8 GB scratch traffic, round-3 regression).

// ---------------- x: NCHW fp32 -> NHWC hi/lo bf16 (512 ch)
__global__ void k_x_split(const float* __restrict__ in, bf16* __restrict__ out) {
  __shared__ float t[32][33];
  const int b = blockIdx.z;
  const int p0 = blockIdx.x << 5, c0 = blockIdx.y << 5;
  const int tx = threadIdx.x, ty = threadIdx.y;  // block (32,8)
  const float* ib = in + (size_t)b * 256 * 16384;
  bf16* ob = out + (size_t)b * 16384 * 512;
#pragma unroll
  for (int k = 0; k < 32; k += 8)
    t[ty + k][tx] = ib[(size_t)(c0 + ty + k) * 16384 + p0 + tx];
  __syncthreads();
#pragma unroll
  for (int k = 0; k < 32; k += 8) {
    float v = t[tx][ty + k];
    bf16 hv = (bf16)v;
    bf16 lv = (bf16)(v - (float)hv);
    ob[(size_t)(p0 + ty + k) * 512 + c0 + tx] = hv;
    ob[(size_t)(p0 + ty + k) * 512 + 256 + c0 + tx] = lv;
  }
}

// ---------------- weight repack fp32 OIHW -> bf16 [2*tap+s][ci_chunk][co][32ci]
// (s=0 Wh, s=1 Wl). Per-(seg,tap) block is chunk-major so a wave's MFMA A
// fragment (16 co x 32 ci) is 1KB contiguous.
__global__ void k_repack2(const float* __restrict__ src, bf16* __restrict__ dst,
                          int Cout, int Cin, int taps, int coutTotal, int coff) {
  int tid = blockIdx.x * 256 + threadIdx.x;
  int total = Cout * Cin * taps;
  if (tid >= total) return;
  int t = tid % taps;
  int rest = tid / taps;
  int ci = rest % Cin;
  int co = rest / Cin;
  float w = src[tid];
  bf16 wh = (bf16)w;
  bf16 wl = (bf16)(w - (float)wh);
  int nchunk = Cin >> 5;
  size_t segsz = (size_t)coutTotal * Cin;  // = nchunk*coutTotal*32
  size_t base = (((size_t)(2 * t) * nchunk + (ci >> 5)) * coutTotal + coff + co) * 32
                + (ci & 31);
  dst[base] = wh;
  dst[base + segsz] = wl;
}

// ---------------- BN coefficients
__global__ void k_bncoef(const float* __restrict__ g, const float* __restrict__ b,
                         const float* __restrict__ m, const float* __restrict__ v,
                         float* __restrict__ sc, float* __restrict__ sh, int n) {
  int c = blockIdx.x * 256 + threadIdx.x;
  if (c >= n) return;
  float s = g[c] * (1.0f / sqrtf(v[c] + 1e-5f));
  sc[c] = s;
  sh[c] = b[c] - m[c] * s;
}

// ---------------- implicit-GEMM conv, A from global (fragment-major), swizzled B slab
// in: hi/lo act tensor (hi at +0, lo at +Cin within rowStride-ch rows).
// out_mode: 0 = hi/lo bf16 NHWC (2*Cout ch), 1 = fp32 NHWC compact,
// 2 = fp32 NCHW. addbuf: hi/lo, stride 2*Cout. Block covers NW*32 cout x 128 pos.
template <int NTAPS, int NW>
__global__ __launch_bounds__(NW * 64, 3)
void k_conv(const bf16* __restrict__ in, int Cin, int rowStride,
            const bf16* __restrict__ Wr, int Cout,
            const float* __restrict__ scale, const float* __restrict__ shift,
            const bf16* __restrict__ addbuf, int relu,
            int out_mode, void* __restrict__ out) {
  constexpr int R = (NTAPS == 9) ? 3 : 1;
  constexpr int NT = NW * 64;
  __shared__ bf16 b_slab[2 * R * 130 * 32];  // plane = hl*R + r; pos -1..128 at +1
  const int bx = blockIdx.x;
  const int bb = bx & 7, h = (bx >> 3) & 127;   // XCD swizzle: batch == XCD
  const int row = bb * 128 + h;
  const int co_block = blockIdx.y * (NW * 32);
  const int tid = threadIdx.x;
  const int lane = tid & 63, wave = tid >> 6;
  const int wm = (wave >> 1) << 6, wn = (wave & 1) << 6;
  const int quad = lane >> 4, l15 = lane & 15;
  const int nchunk = Cin >> 5;
  const size_t segsz = (size_t)Cout * Cin;  // seg stride in repacked weights

  f32x4 acc[4][4];
#pragma unroll
  for (int i = 0; i < 4; ++i)
#pragma unroll
    for (int j = 0; j < 4; ++j)
#pragma unroll
      for (int r = 0; r < 4; ++r) acc[i][j][r] = 0.0f;

  constexpr int nunits = 2 * R * 130;

  for (int cb = 0; cb < Cin; cb += 32) {
    // ---- stage B slab (once per chunk): 2(hl) x R rows x 130 pos x 32 ch
    // XOR-swizzled: granule s (8ch) of row p stored at slot s ^ ((p>>1)&3)
    for (int u = tid; u < nunits; u += NT) {
      int plane = u / 130, p = u - plane * 130;
      int hl, r;
      if (R == 3) { hl = plane >= 3; r = plane - (hl ? 3 : 0); }
      else        { hl = plane; r = 0; }
      int hi = h + r - (R == 3 ? 1 : 0);
      int wi = p - 1;
      uint4 v0, v1, v2, v3;
      v0.x = v0.y = v0.z = v0.w = 0u; v1 = v0; v2 = v0; v3 = v0;
      if ((unsigned)hi < 128u && (unsigned)wi < 128u) {
        const bf16* s = in + (size_t)((bb * 128 + hi) * 128 + wi) * rowStride
                        + (size_t)hl * Cin + cb;
        v0 = *(const uint4*)s;
        v1 = *(const uint4*)(s + 8);
        v2 = *(const uint4*)(s + 16);
        v3 = *(const uint4*)(s + 24);
      }
      bf16* d = &b_slab[(size_t)(plane * 130 + p) * 32];
      const int sw = (p >> 1) & 3;
      *(uint4*)(d + ((0 ^ sw) << 3)) = v0;
      *(uint4*)(d + ((1 ^ sw) << 3)) = v1;
      *(uint4*)(d + ((2 ^ sw) << 3)) = v2;
      *(uint4*)(d + ((3 ^ sw) << 3)) = v3;
    }
    __syncthreads();
#pragma unroll
    for (int tap = 0; tap < NTAPS; ++tap) {
      const int rr = (R == 3) ? (tap / 3) : 0;        // slab row
      const int wc = (R == 3) ? (tap % 3) : 1;        // dw+1 column offset
      const int bH = rr * 130;
      const int bL = (R + rr) * 130;
      const int p0 = wn + l15 + wc;                   // j=0 position (j adds 16)
      const int sw8 = (((p0 >> 1) & 3) ^ quad) << 3;  // invariant across j
      // ---- A fragments straight from L2; fragment-major layout:
      // lane addr = l15*64B + quad*16B -> one coalesced 1KB load per fragment
      const bf16* Ah = Wr + (((size_t)(2 * tap) * nchunk + (cb >> 5)) * Cout
                             + co_block + wm + l15) * 32 + quad * 8;
      const bf16* Al = Ah + segsz;
      bf16x8 afH[4], afL[4], bfH[4], bfL[4];
#pragma unroll
      for (int i = 0; i < 4; ++i) {
        afH[i] = *(const bf16x8*)(Ah + (size_t)i * 16 * 32);
        afL[i] = *(const bf16x8*)(Al + (size_t)i * 16 * 32);
      }
#pragma unroll
      for (int j = 0; j < 4; ++j) {
        const int p_idx = p0 + j * 16;
        bfH[j] = *(const bf16x8*)&b_slab[(size_t)(bH + p_idx) * 32 + sw8];
        bfL[j] = *(const bf16x8*)&b_slab[(size_t)(bL + p_idx) * 32 + sw8];
      }
#pragma unroll
      for (int i = 0; i < 4; ++i)
#pragma unroll
        for (int j = 0; j < 4; ++j) {
          acc[i][j] = __builtin_amdgcn_mfma_f32_16x16x32_bf16(afH[i], bfH[j], acc[i][j], 0, 0, 0);
          acc[i][j] = __builtin_amdgcn_mfma_f32_16x16x32_bf16(afH[i], bfL[j], acc[i][j], 0, 0, 0);
          acc[i][j] = __builtin_amdgcn_mfma_f32_16x16x32_bf16(afL[i], bfH[j], acc[i][j], 0, 0, 0);
        }
    }
    __syncthreads();  // slab reads done before next chunk's restage
  }

  // epilogue: D row(m=cout)=quad*4+reg, col(n=pos)=lane&15
#pragma unroll
  for (int i = 0; i < 4; ++i) {
    const int co = co_block + wm + i * 16 + (quad << 2);
#pragma unroll
    for (int j = 0; j < 4; ++j) {
      const int pos = wn + j * 16 + l15;
      float v[4];
#pragma unroll
      for (int r = 0; r < 4; ++r) v[r] = acc[i][j][r];
      if (scale) {
#pragma unroll
        for (int r = 0; r < 4; ++r) v[r] = v[r] * scale[co + r] + shift[co + r];
      }
      if (addbuf) {
        const bf16* ah = addbuf + (size_t)(row * 128 + pos) * (2 * Cout) + co;
        const bf16* al = ah + Cout;
#pragma unroll
        for (int r = 0; r < 4; ++r) v[r] += (float)ah[r] + (float)al[r];
      }
      if (relu) {
#pragma unroll
        for (int r = 0; r < 4; ++r) v[r] = fmaxf(v[r], 0.0f);
      }
      if (out_mode == 0) {
        bf16* ob = (bf16*)out;
        union { bf16 hv[4]; uint2 u; } ph, pl;
#pragma unroll
        for (int r = 0; r < 4; ++r) {
          ph.hv[r] = (bf16)v[r];
          pl.hv[r] = (bf16)(v[r] - (float)ph.hv[r]);
        }
        const size_t base = (size_t)(row * 128 + pos) * (2 * Cout);
        *(uint2*)&ob[base + co] = ph.u;
        *(uint2*)&ob[base + Cout + co] = pl.u;
      } else if (out_mode == 1) {
        float* of = (float*)out;
        float4 pk = make_float4(v[0], v[1], v[2], v[3]);
        *(float4*)&of[(size_t)(row * 128 + pos) * Cout + co] = pk;
      } else {
        float* of = (float*)out;
#pragma unroll
        for (int r = 0; r < 4; ++r)
          of[((size_t)(bb * Cout + co + r) * 128 + h) * 128 + pos] = v[r];
      }
    }
  }
}

// ---------------- pools (fp32 reconstruct, scan, re-split), in-place
// y: 512ch rows [lookH 0:128 | pH 128:256 | lookL 256:384 | pL 384:512]
__global__ void k_pool_s1(bf16* __restrict__ y) {  // left_pool: scan w
  int tid = blockIdx.x * 256 + threadIdx.x;
  int c = tid & 127, h = (tid >> 7) & 127, b = tid >> 14;
  bf16* base = y + (size_t)((b * 128 + h) * 128) * 512;
  float run = -INFINITY;
  for (int w = 127; w >= 0; --w) {
    bf16* p = base + (size_t)w * 512;
    float look = (float)p[c] + (float)p[256 + c];
    float padd = (float)p[128 + c] + (float)p[384 + c];
    run = fmaxf(run, look);
    float sum = run + padd;
    bf16 hv = (bf16)sum;
    p[c] = hv;
    p[128 + c] = (bf16)(sum - (float)hv);
  }
}
__global__ void k_pool_s2(bf16* __restrict__ y) {  // top_pool: scan h
  int tid = blockIdx.x * 256 + threadIdx.x;
  int c = tid & 127, w = (tid >> 7) & 127, b = tid >> 14;
  bf16* base = y + ((size_t)b * 16384 + w) * 512;
  float run = -INFINITY;
  for (int hh = 127; hh >= 0; --hh) {
    bf16* p = base + (size_t)hh * 65536;
    float look = (float)p[c] + (float)p[256 + c];
    float padd = (float)p[128 + c] + (float)p[384 + c];
    run = fmaxf(run, look);
    float sum = run + padd;
    bf16 hv = (bf16)sum;
    p[c] = hv;
    p[128 + c] = (bf16)(sum - (float)hv);
  }
}
__global__ void k_tpool_f(float* __restrict__ buf) {  // in-place top_pool fp32
  int tid = blockIdx.x * 256 + threadIdx.x;
  int c = tid & 127, w = (tid >> 7) & 127, b = tid >> 14;
  float* p = buf + ((size_t)b * 16384 + w) * 128 + c;
  float run = -INFINITY;
  for (int hh = 127; hh >= 0; --hh) {
    run = fmaxf(run, p[(size_t)hh * 16384]);
    p[(size_t)hh * 16384] = run;
  }
}
__global__ void k_lpool_add_f(const float* __restrict__ in, const float* __restrict__ addb,
                              bf16* __restrict__ out) {
  int tid = blockIdx.x * 256 + threadIdx.x;
  int c = tid & 127, h = (tid >> 7) & 127, b = tid >> 14;
  const float* p = in + (size_t)((b * 128 + h) * 128) * 128 + c;
  const float* a = addb + (size_t)((b * 128 + h) * 128) * 128 + c;
  bf16* o = out + (size_t)((b * 128 + h) * 128) * 256;
  float run = -INFINITY;
  for (int w = 127; w >= 0; --w) {
    run = fmaxf(run, p[(size_t)w * 128]);
    float sum = run + a[(size_t)w * 128];
    bf16 hv = (bf16)sum;
    o[(size_t)w * 256 + c] = hv;
    o[(size_t)w * 256 + 128 + c] = (bf16)(sum - (float)hv);
  }
}

extern "C" void kernel_launch(void* const* d_in, const int* in_sizes, int n_in,
                              void* d_out, int out_size, void* d_ws, size_t ws_size,
                              hipStream_t stream) {
  (void)in_sizes; (void)n_in; (void)out_size; (void)ws_size;
#define INF(i) ((const float*)d_in[i])
  char* ws = (char*)d_ws;
  const size_t MB = 1 << 20;
  // weights [0, ~9.75MB): [2*tap+s][ci_chunk][co][32]
  bf16* wrA  = (bf16*)(ws + 0);          // 18*256*256
  bf16* wrB  = (bf16*)(ws + 2359296);
  bf16* wrp1 = (bf16*)(ws + 4718592);    // 18*128*128
  bf16* wrp2 = (bf16*)(ws + 5308416);
  bf16* wrpc = (bf16*)(ws + 5898240);    // 18*256*128
  bf16* wrc1 = (bf16*)(ws + 7077888);    // 2*256*256
  bf16* wrc2 = (bf16*)(ws + 7340032);    // 18*256*256
  float* scA  = (float*)(ws + 9699328);
  float* shA  = (float*)(ws + 9703424);
  float* scB  = (float*)(ws + 9707520);
  float* shB  = (float*)(ws + 9711616);
  float* scp  = (float*)(ws + 9715712);
  float* shp  = (float*)(ws + 9719808);
  float* scb  = (float*)(ws + 9723904);
  float* shb  = (float*)(ws + 9728000);
  float* scc2 = (float*)(ws + 9732096);
  float* shc2 = (float*)(ws + 9736192);
  // activations (ws use <= 330 MB; d_out doubles as 128 MB scratch)
  bf16*  x_hl  = (bf16*)(ws + 10 * MB);    // 128 MB, live thru step 8
  bf16*  bnrel = (bf16*)(ws + 138 * MB);   // 128 MB: bn1 -> relu1 in-place
  float* p1lk  = (float*)(ws + 266 * MB);  // 64 MB fp32
  float* p2lk  = (float*)(ws + 10 * MB);   // 64 MB fp32 over dead x_hl
  bf16*  psum  = (bf16*)(ws + 74 * MB);    // 64 MB hi/lo compact 256ch
  bf16*  yscr  = (bf16*)d_out;             // 128 MB scratch: yA/s1 then yB/s2

  // 1) x -> NHWC hi/lo
  k_x_split<<<dim3(512, 8, 8), dim3(32, 8), 0, stream>>>(INF(0), x_hl);

  // 2) weight repacks (Wh/Wl segments)
  k_repack2<<<1152, 256, 0, stream>>>(INF(1),  wrA,  128, 256, 9, 256, 0);
  k_repack2<<<1152, 256, 0, stream>>>(INF(6),  wrA,  128, 256, 9, 256, 128);
  k_repack2<<<1152, 256, 0, stream>>>(INF(11), wrB,  128, 256, 9, 256, 0);
  k_repack2<<<1152, 256, 0, stream>>>(INF(16), wrB,  128, 256, 9, 256, 128);
  k_repack2<<<576,  256, 0, stream>>>(INF(21), wrp1, 128, 128, 9, 128, 0);
  k_repack2<<<576,  256, 0, stream>>>(INF(22), wrp2, 128, 128, 9, 128, 0);
  k_repack2<<<1152, 256, 0, stream>>>(INF(23), wrpc, 256, 128, 9, 256, 0);
  k_repack2<<<256,  256, 0, stream>>>(INF(28), wrc1, 256, 256, 1, 256, 0);
  k_repack2<<<2304, 256, 0, stream>>>(INF(33), wrc2, 256, 256, 9, 256, 0);

  // 3) BN coefficients
  k_bncoef<<<1, 256, 0, stream>>>(INF(2),  INF(3),  INF(4),  INF(5),  scA,       shA,       128);
  k_bncoef<<<1, 256, 0, stream>>>(INF(7),  INF(8),  INF(9),  INF(10), scA + 128, shA + 128, 128);
  k_bncoef<<<1, 256, 0, stream>>>(INF(12), INF(13), INF(14), INF(15), scB,       shB,       128);
  k_bncoef<<<1, 256, 0, stream>>>(INF(17), INF(18), INF(19), INF(20), scB + 128, shB + 128, 128);
  k_bncoef<<<1, 256, 0, stream>>>(INF(24), INF(25), INF(26), INF(27), scp, shp, 256);
  k_bncoef<<<1, 256, 0, stream>>>(INF(29), INF(30), INF(31), INF(32), scb, shb, 256);
  k_bncoef<<<1, 256, 0, stream>>>(INF(34), INF(35), INF(36), INF(37), scc2, shc2, 256);

  // 4) bn1 = BN(conv1x1(x)) -> bnrel (hi/lo)
  k_conv<1, 8><<<dim3(1024, 1), 512, 0, stream>>>(x_hl, 256, 512, wrc1, 256, scb, shb, nullptr, 0, 0, bnrel);
  // 5) yA = [look_conv1 | p1_conv1] (BN+ReLU) -> d_out scratch
  k_conv<9, 8><<<dim3(1024, 1), 512, 0, stream>>>(x_hl, 256, 512, wrA, 256, scA, shA, nullptr, 1, 0, yscr);
  // 6) s1 = left_pool(look1) + p1_conv1 (in-place, ch [0:256))
  k_pool_s1<<<512, 256, 0, stream>>>(yscr);
  // 7) p1_look = conv(s1, p1lc) -> fp32
  k_conv<9, 4><<<dim3(1024, 1), 256, 0, stream>>>(yscr, 128, 512, wrp1, 128, nullptr, nullptr, nullptr, 0, 1, p1lk);
  // 8) yB = [look_conv2 | p2_conv1] -> d_out scratch (x dead after)
  k_conv<9, 8><<<dim3(1024, 1), 512, 0, stream>>>(x_hl, 256, 512, wrB, 256, scB, shB, nullptr, 1, 0, yscr);
  // 9) s2 = top_pool(look2) + p2_conv1 (in-place)
  k_pool_s2<<<512, 256, 0, stream>>>(yscr);
  // 10) p2_look = conv(s2, p2lc) -> fp32 (over dead x_hl)
  k_conv<9, 4><<<dim3(1024, 1), 256, 0, stream>>>(yscr, 128, 512, wrp2, 128, nullptr, nullptr, nullptr, 0, 1, p2lk);
  // 11) ptmp = top_pool(p1_look) in-place
  k_tpool_f<<<512, 256, 0, stream>>>(p1lk);
  // 12) psum = left_pool(p2_look) + ptmp -> hi/lo compact
  k_lpool_add_f<<<512, 256, 0, stream>>>(p2lk, p1lk, psum);
  // 13) relu1 = relu(BN(conv(psum, pconv1)) + bn1) in-place over bn1
  k_conv<9, 8><<<dim3(1024, 1), 512, 0, stream>>>(psum, 128, 256, wrpc, 256, scp, shp, bnrel, 1, 0, bnrel);
  // 14) out = relu(BN(conv(relu1, c2))) -> NCHW fp32 d_out
  k_conv<9, 8><<<dim3(1024, 1), 512, 0, stream>>>(bnrel, 256, 512, wrc2, 256, scc2, shc2, nullptr, 1, 2, (float*)d_out);
#undef INF
}

// Round 5
// 2825.810 us; speedup vs baseline: 5.0257x; 1.3904x over previous
//
#include <hip/hip_runtime.h>
#include <hip/hip_bf16.h>
#include <stdint.h>
#include <math.h>

typedef __bf16 bf16;
typedef __bf16 bf16x8 __attribute__((ext_vector_type(8)));
typedef float f32x16 __attribute__((ext_vector_type(16)));

// B=8, H=W=128, dim=256, mid=128. fp32 I/O; internal hi/lo bf16 pairs.
// conv = 3-term bf16 (WhAh + WhAl + WlAh) on 32x32x16 MFMA (2495 TF pipe, half
// the instruction count of 16x16x32). A loaded global->reg per tap from a
// fragment-major repack [2*tap+s][ci_chunk][kh][co][16ci] (contiguous 1KB
// wave-loads, L2-resident); B staged once per K-chunk in an XOR-swizzled LDS
// slab; no per-tap barriers. NW=4 (256 thr) blocks, grid-y over cout —
// the NW=8 merge regressed twice (occupancy collapse), do not retry.

// ---------------- x: NCHW fp32 -> NHWC hi/lo bf16 (512 ch)
__global__ void k_x_split(const float* __restrict__ in, bf16* __restrict__ out) {
  __shared__ float t[32][33];
  const int b = blockIdx.z;
  const int p0 = blockIdx.x << 5, c0 = blockIdx.y << 5;
  const int tx = threadIdx.x, ty = threadIdx.y;  // block (32,8)
  const float* ib = in + (size_t)b * 256 * 16384;
  bf16* ob = out + (size_t)b * 16384 * 512;
#pragma unroll
  for (int k = 0; k < 32; k += 8)
    t[ty + k][tx] = ib[(size_t)(c0 + ty + k) * 16384 + p0 + tx];
  __syncthreads();
#pragma unroll
  for (int k = 0; k < 32; k += 8) {
    float v = t[tx][ty + k];
    bf16 hv = (bf16)v;
    bf16 lv = (bf16)(v - (float)hv);
    ob[(size_t)(p0 + ty + k) * 512 + c0 + tx] = hv;
    ob[(size_t)(p0 + ty + k) * 512 + 256 + c0 + tx] = lv;
  }
}

// ---------------- weight repack fp32 OIHW -> bf16 [2*tap+s][ci_chunk][kh][co][16ci]
// (s=0 Wh, s=1 Wl; kh = 16-ci half within the 32-ci chunk). A wave's 32x32x16
// MFMA A fragment (32 co x 16 ci) is 1KB contiguous.
__global__ void k_repack2(const float* __restrict__ src, bf16* __restrict__ dst,
                          int Cout, int Cin, int taps, int coutTotal, int coff) {
  int tid = blockIdx.x * 256 + threadIdx.x;
  int total = Cout * Cin * taps;
  if (tid >= total) return;
  int t = tid % taps;
  int rest = tid / taps;
  int ci = rest % Cin;
  int co = rest / Cin;
  float w = src[tid];
  bf16 wh = (bf16)w;
  bf16 wl = (bf16)(w - (float)wh);
  int nchunk = Cin >> 5;
  size_t segsz = (size_t)coutTotal * Cin;
  size_t base = ((((size_t)(2 * t) * nchunk + (ci >> 5)) * 2 + ((ci >> 4) & 1)) * coutTotal
                 + coff + co) * 16 + (ci & 15);
  dst[base] = wh;
  dst[base + segsz] = wl;
}

// ---------------- BN coefficients
__global__ void k_bncoef(const float* __restrict__ g, const float* __restrict__ b,
                         const float* __restrict__ m, const float* __restrict__ v,
                         float* __restrict__ sc, float* __restrict__ sh, int n) {
  int c = blockIdx.x * 256 + threadIdx.x;
  if (c >= n) return;
  float s = g[c] * (1.0f / sqrtf(v[c] + 1e-5f));
  sc[c] = s;
  sh[c] = b[c] - m[c] * s;
}

// ---------------- implicit-GEMM conv, A from global (fragment-major), swizzled B slab
// 32x32x16 MFMA. in: hi/lo act tensor (hi at +0, lo at +Cin within rowStride-ch
// rows). out_mode: 0 = hi/lo bf16 NHWC (2*Cout ch), 1 = fp32 NHWC compact,
// 2 = fp32 NCHW. addbuf: hi/lo, stride 2*Cout. Block = 128 cout x 128 pos.
template <int NTAPS>
__global__ __launch_bounds__(256, 3)
void k_conv(const bf16* __restrict__ in, int Cin, int rowStride,
            const bf16* __restrict__ Wr, int Cout,
            const float* __restrict__ scale, const float* __restrict__ shift,
            const bf16* __restrict__ addbuf, int relu,
            int out_mode, void* __restrict__ out) {
  constexpr int R = (NTAPS == 9) ? 3 : 1;
  __shared__ bf16 b_slab[2 * R * 130 * 32];  // plane = hl*R + r; pos -1..128 at +1
  const int bx = blockIdx.x;
  const int bb = bx & 7, h = (bx >> 3) & 127;   // XCD swizzle: batch == XCD
  const int row = bb * 128 + h;
  const int co_block = blockIdx.y << 7;
  const int tid = threadIdx.x;
  const int lane = tid & 63, wave = tid >> 6;
  const int wm = (wave >> 1) << 6, wn = (wave & 1) << 6;
  const int col = lane & 31, kg = lane >> 5;    // 32x32 fragment lane roles
  const int nchunk = Cin >> 5;
  const size_t segsz = (size_t)Cout * Cin;      // seg stride in repacked weights

  f32x16 acc[2][2];
#pragma unroll
  for (int i = 0; i < 2; ++i)
#pragma unroll
    for (int j = 0; j < 2; ++j)
#pragma unroll
      for (int r = 0; r < 16; ++r) acc[i][j][r] = 0.0f;

  constexpr int nunits = 2 * R * 130;

  for (int cb = 0; cb < Cin; cb += 32) {
    // ---- stage B slab (once per chunk): 2(hl) x R rows x 130 pos x 32 ch
    // XOR-swizzled: granule s (8ch=16B) of row p stored at slot s ^ ((p>>1)&3)
    for (int u = tid; u < nunits; u += 256) {
      int plane = u / 130, p = u - plane * 130;
      int hl, r;
      if (R == 3) { hl = plane >= 3; r = plane - (hl ? 3 : 0); }
      else        { hl = plane; r = 0; }
      int hi = h + r - (R == 3 ? 1 : 0);
      int wi = p - 1;
      uint4 v0, v1, v2, v3;
      v0.x = v0.y = v0.z = v0.w = 0u; v1 = v0; v2 = v0; v3 = v0;
      if ((unsigned)hi < 128u && (unsigned)wi < 128u) {
        const bf16* s = in + (size_t)((bb * 128 + hi) * 128 + wi) * rowStride
                        + (size_t)hl * Cin + cb;
        v0 = *(const uint4*)s;
        v1 = *(const uint4*)(s + 8);
        v2 = *(const uint4*)(s + 16);
        v3 = *(const uint4*)(s + 24);
      }
      bf16* d = &b_slab[(size_t)(plane * 130 + p) * 32];
      const int sw = (p >> 1) & 3;
      *(uint4*)(d + ((0 ^ sw) << 3)) = v0;
      *(uint4*)(d + ((1 ^ sw) << 3)) = v1;
      *(uint4*)(d + ((2 ^ sw) << 3)) = v2;
      *(uint4*)(d + ((3 ^ sw) << 3)) = v3;
    }
    __syncthreads();
#pragma unroll
    for (int tap = 0; tap < NTAPS; ++tap) {
      const int rr = (R == 3) ? (tap / 3) : 0;        // slab row
      const int wc = (R == 3) ? (tap % 3) : 1;        // dw+1 column offset
      const int bH = rr * 130;
      const int bL = (R + rr) * 130;
      // ---- A fragments straight from L2; [seg][chunk][kh][co][16] layout:
      // lane addr = col*32B + kg*16B -> one contiguous 1KB load per fragment
      const bf16* A0 = Wr + ((((size_t)(2 * tap) * nchunk + (cb >> 5)) * 2) * Cout
                             + co_block + wm + col) * 16 + kg * 8;
      bf16x8 afH[2][2], afL[2][2], bfH[2][2], bfL[2][2];  // [ti|tj][kh]
#pragma unroll
      for (int ti = 0; ti < 2; ++ti)
#pragma unroll
        for (int kh = 0; kh < 2; ++kh) {
          const bf16* a = A0 + (size_t)kh * Cout * 16 + ti * 32 * 16;
          afH[ti][kh] = *(const bf16x8*)a;
          afL[ti][kh] = *(const bf16x8*)(a + segsz);
        }
#pragma unroll
      for (int tj = 0; tj < 2; ++tj)
#pragma unroll
        for (int kh = 0; kh < 2; ++kh) {
          const int p = wn + tj * 32 + col + wc;
          const int slot = ((kh << 1) + kg) ^ ((p >> 1) & 3);
          bfH[tj][kh] = *(const bf16x8*)&b_slab[(size_t)(bH + p) * 32 + slot * 8];
          bfL[tj][kh] = *(const bf16x8*)&b_slab[(size_t)(bL + p) * 32 + slot * 8];
        }
#pragma unroll
      for (int ti = 0; ti < 2; ++ti)
#pragma unroll
        for (int tj = 0; tj < 2; ++tj)
#pragma unroll
          for (int kh = 0; kh < 2; ++kh) {
            acc[ti][tj] = __builtin_amdgcn_mfma_f32_32x32x16_bf16(afH[ti][kh], bfH[tj][kh], acc[ti][tj], 0, 0, 0);
            acc[ti][tj] = __builtin_amdgcn_mfma_f32_32x32x16_bf16(afH[ti][kh], bfL[tj][kh], acc[ti][tj], 0, 0, 0);
            acc[ti][tj] = __builtin_amdgcn_mfma_f32_32x32x16_bf16(afL[ti][kh], bfH[tj][kh], acc[ti][tj], 0, 0, 0);
          }
    }
    __syncthreads();  // slab reads done before next chunk's restage
  }

  // epilogue: 32x32 D layout: col(n=pos)=lane&31, row(m=cout)=(reg&3)+8*(reg>>2)+4*kg
#pragma unroll
  for (int ti = 0; ti < 2; ++ti)
#pragma unroll
    for (int tj = 0; tj < 2; ++tj)
#pragma unroll
      for (int g = 0; g < 4; ++g) {
        const int co = co_block + wm + ti * 32 + g * 8 + kg * 4;
        const int pos = wn + tj * 32 + col;
        float v[4];
#pragma unroll
        for (int r = 0; r < 4; ++r) v[r] = acc[ti][tj][g * 4 + r];
        if (scale) {
#pragma unroll
          for (int r = 0; r < 4; ++r) v[r] = v[r] * scale[co + r] + shift[co + r];
        }
        if (addbuf) {
          const bf16* ah = addbuf + (size_t)(row * 128 + pos) * (2 * Cout) + co;
          const bf16* al = ah + Cout;
#pragma unroll
          for (int r = 0; r < 4; ++r) v[r] += (float)ah[r] + (float)al[r];
        }
        if (relu) {
#pragma unroll
          for (int r = 0; r < 4; ++r) v[r] = fmaxf(v[r], 0.0f);
        }
        if (out_mode == 0) {
          bf16* ob = (bf16*)out;
          union { bf16 hv[4]; uint2 u; } ph, pl;
#pragma unroll
          for (int r = 0; r < 4; ++r) {
            ph.hv[r] = (bf16)v[r];
            pl.hv[r] = (bf16)(v[r] - (float)ph.hv[r]);
          }
          const size_t base = (size_t)(row * 128 + pos) * (2 * Cout);
          *(uint2*)&ob[base + co] = ph.u;
          *(uint2*)&ob[base + Cout + co] = pl.u;
        } else if (out_mode == 1) {
          float* of = (float*)out;
          float4 pk = make_float4(v[0], v[1], v[2], v[3]);
          *(float4*)&of[(size_t)(row * 128 + pos) * Cout + co] = pk;
        } else {
          float* of = (float*)out;
#pragma unroll
          for (int r = 0; r < 4; ++r)
            of[((size_t)(bb * Cout + co + r) * 128 + h) * 128 + pos] = v[r];
        }
      }
}

// ---------------- pools (fp32 reconstruct, scan, re-split), in-place
// y: 512ch rows [lookH 0:128 | pH 128:256 | lookL 256:384 | pL 384:512]
__global__ void k_pool_s1(bf16* __restrict__ y) {  // left_pool: scan w
  int tid = blockIdx.x * 256 + threadIdx.x;
  int c = tid & 127, h = (tid >> 7) & 127, b = tid >> 14;
  bf16* base = y + (size_t)((b * 128 + h) * 128) * 512;
  float run = -INFINITY;
  for (int w = 127; w >= 0; --w) {
    bf16* p = base + (size_t)w * 512;
    float look = (float)p[c] + (float)p[256 + c];
    float padd = (float)p[128 + c] + (float)p[384 + c];
    run = fmaxf(run, look);
    float sum = run + padd;
    bf16 hv = (bf16)sum;
    p[c] = hv;
    p[128 + c] = (bf16)(sum - (float)hv);
  }
}
__global__ void k_pool_s2(bf16* __restrict__ y) {  // top_pool: scan h
  int tid = blockIdx.x * 256 + threadIdx.x;
  int c = tid & 127, w = (tid >> 7) & 127, b = tid >> 14;
  bf16* base = y + ((size_t)b * 16384 + w) * 512;
  float run = -INFINITY;
  for (int hh = 127; hh >= 0; --hh) {
    bf16* p = base + (size_t)hh * 65536;
    float look = (float)p[c] + (float)p[256 + c];
    float padd = (float)p[128 + c] + (float)p[384 + c];
    run = fmaxf(run, look);
    float sum = run + padd;
    bf16 hv = (bf16)sum;
    p[c] = hv;
    p[128 + c] = (bf16)(sum - (float)hv);
  }
}
__global__ void k_tpool_f(float* __restrict__ buf) {  // in-place top_pool fp32
  int tid = blockIdx.x * 256 + threadIdx.x;
  int c = tid & 127, w = (tid >> 7) & 127, b = tid >> 14;
  float* p = buf + ((size_t)b * 16384 + w) * 128 + c;
  float run = -INFINITY;
  for (int hh = 127; hh >= 0; --hh) {
    run = fmaxf(run, p[(size_t)hh * 16384]);
    p[(size_t)hh * 16384] = run;
  }
}
__global__ void k_lpool_add_f(const float* __restrict__ in, const float* __restrict__ addb,
                              bf16* __restrict__ out) {
  int tid = blockIdx.x * 256 + threadIdx.x;
  int c = tid & 127, h = (tid >> 7) & 127, b = tid >> 14;
  const float* p = in + (size_t)((b * 128 + h) * 128) * 128 + c;
  const float* a = addb + (size_t)((b * 128 + h) * 128) * 128 + c;
  bf16* o = out + (size_t)((b * 128 + h) * 128) * 256;
  float run = -INFINITY;
  for (int w = 127; w >= 0; --w) {
    run = fmaxf(run, p[(size_t)w * 128]);
    float sum = run + a[(size_t)w * 128];
    bf16 hv = (bf16)sum;
    o[(size_t)w * 256 + c] = hv;
    o[(size_t)w * 256 + 128 + c] = (bf16)(sum - (float)hv);
  }
}

extern "C" void kernel_launch(void* const* d_in, const int* in_sizes, int n_in,
                              void* d_out, int out_size, void* d_ws, size_t ws_size,
                              hipStream_t stream) {
  (void)in_sizes; (void)n_in; (void)out_size; (void)ws_size;
#define INF(i) ((const float*)d_in[i])
  char* ws = (char*)d_ws;
  const size_t MB = 1 << 20;
  // weights [0, ~9.75MB): [2*tap+s][ci_chunk][kh][co][16]
  bf16* wrA  = (bf16*)(ws + 0);          // 18*256*256
  bf16* wrB  = (bf16*)(ws + 2359296);
  bf16* wrp1 = (bf16*)(ws + 4718592);    // 18*128*128
  bf16* wrp2 = (bf16*)(ws + 5308416);
  bf16* wrpc = (bf16*)(ws + 5898240);    // 18*256*128
  bf16* wrc1 = (bf16*)(ws + 7077888);    // 2*256*256
  bf16* wrc2 = (bf16*)(ws + 7340032);    // 18*256*256
  float* scA  = (float*)(ws + 9699328);
  float* shA  = (float*)(ws + 9703424);
  float* scB  = (float*)(ws + 9707520);
  float* shB  = (float*)(ws + 9711616);
  float* scp  = (float*)(ws + 9715712);
  float* shp  = (float*)(ws + 9719808);
  float* scb  = (float*)(ws + 9723904);
  float* shb  = (float*)(ws + 9728000);
  float* scc2 = (float*)(ws + 9732096);
  float* shc2 = (float*)(ws + 9736192);
  // activations (ws use <= 330 MB; d_out doubles as 128 MB scratch)
  bf16*  x_hl  = (bf16*)(ws + 10 * MB);    // 128 MB, live thru step 8
  bf16*  bnrel = (bf16*)(ws + 138 * MB);   // 128 MB: bn1 -> relu1 in-place
  float* p1lk  = (float*)(ws + 266 * MB);  // 64 MB fp32
  float* p2lk  = (float*)(ws + 10 * MB);   // 64 MB fp32 over dead x_hl
  bf16*  psum  = (bf16*)(ws + 74 * MB);    // 64 MB hi/lo compact 256ch
  bf16*  yscr  = (bf16*)d_out;             // 128 MB scratch: yA/s1 then yB/s2

  // 1) x -> NHWC hi/lo
  k_x_split<<<dim3(512, 8, 8), dim3(32, 8), 0, stream>>>(INF(0), x_hl);

  // 2) weight repacks (Wh/Wl segments)
  k_repack2<<<1152, 256, 0, stream>>>(INF(1),  wrA,  128, 256, 9, 256, 0);
  k_repack2<<<1152, 256, 0, stream>>>(INF(6),  wrA,  128, 256, 9, 256, 128);
  k_repack2<<<1152, 256, 0, stream>>>(INF(11), wrB,  128, 256, 9, 256, 0);
  k_repack2<<<1152, 256, 0, stream>>>(INF(16), wrB,  128, 256, 9, 256, 128);
  k_repack2<<<576,  256, 0, stream>>>(INF(21), wrp1, 128, 128, 9, 128, 0);
  k_repack2<<<576,  256, 0, stream>>>(INF(22), wrp2, 128, 128, 9, 128, 0);
  k_repack2<<<1152, 256, 0, stream>>>(INF(23), wrpc, 256, 128, 9, 256, 0);
  k_repack2<<<256,  256, 0, stream>>>(INF(28), wrc1, 256, 256, 1, 256, 0);
  k_repack2<<<2304, 256, 0, stream>>>(INF(33), wrc2, 256, 256, 9, 256, 0);

  // 3) BN coefficients
  k_bncoef<<<1, 256, 0, stream>>>(INF(2),  INF(3),  INF(4),  INF(5),  scA,       shA,       128);
  k_bncoef<<<1, 256, 0, stream>>>(INF(7),  INF(8),  INF(9),  INF(10), scA + 128, shA + 128, 128);
  k_bncoef<<<1, 256, 0, stream>>>(INF(12), INF(13), INF(14), INF(15), scB,       shB,       128);
  k_bncoef<<<1, 256, 0, stream>>>(INF(17), INF(18), INF(19), INF(20), scB + 128, shB + 128, 128);
  k_bncoef<<<1, 256, 0, stream>>>(INF(24), INF(25), INF(26), INF(27), scp, shp, 256);
  k_bncoef<<<1, 256, 0, stream>>>(INF(29), INF(30), INF(31), INF(32), scb, shb, 256);
  k_bncoef<<<1, 256, 0, stream>>>(INF(34), INF(35), INF(36), INF(37), scc2, shc2, 256);

  // 4) bn1 = BN(conv1x1(x)) -> bnrel (hi/lo)
  k_conv<1><<<dim3(1024, 2), 256, 0, stream>>>(x_hl, 256, 512, wrc1, 256, scb, shb, nullptr, 0, 0, bnrel);
  // 5) yA = [look_conv1 | p1_conv1] (BN+ReLU) -> d_out scratch
  k_conv<9><<<dim3(1024, 2), 256, 0, stream>>>(x_hl, 256, 512, wrA, 256, scA, shA, nullptr, 1, 0, yscr);
  // 6) s1 = left_pool(look1) + p1_conv1 (in-place, ch [0:256))
  k_pool_s1<<<512, 256, 0, stream>>>(yscr);
  // 7) p1_look = conv(s1, p1lc) -> fp32
  k_conv<9><<<dim3(1024, 1), 256, 0, stream>>>(yscr, 128, 512, wrp1, 128, nullptr, nullptr, nullptr, 0, 1, p1lk);
  // 8) yB = [look_conv2 | p2_conv1] -> d_out scratch (x dead after)
  k_conv<9><<<dim3(1024, 2), 256, 0, stream>>>(x_hl, 256, 512, wrB, 256, scB, shB, nullptr, 1, 0, yscr);
  // 9) s2 = top_pool(look2) + p2_conv1 (in-place)
  k_pool_s2<<<512, 256, 0, stream>>>(yscr);
  // 10) p2_look = conv(s2, p2lc) -> fp32 (over dead x_hl)
  k_conv<9><<<dim3(1024, 1), 256, 0, stream>>>(yscr, 128, 512, wrp2, 128, nullptr, nullptr, nullptr, 0, 1, p2lk);
  // 11) ptmp = top_pool(p1_look) in-place
  k_tpool_f<<<512, 256, 0, stream>>>(p1lk);
  // 12) psum = left_pool(p2_look) + ptmp -> hi/lo compact
  k_lpool_add_f<<<512, 256, 0, stream>>>(p2lk, p1lk, psum);
  // 13) relu1 = relu(BN(conv(psum, pconv1)) + bn1) in-place over bn1
  k_conv<9><<<dim3(1024, 2), 256, 0, stream>>>(psum, 128, 256, wrpc, 256, scp, shp, bnrel, 1, 0, bnrel);
  // 14) out = relu(BN(conv(relu1, c2))) -> NCHW fp32 d_out
  k_conv<9><<<dim3(1024, 2), 256, 0, stream>>>(bnrel, 256, 512, wrc2, 256, scc2, shc2, nullptr, 1, 2, (float*)d_out);
#undef INF
}

// Round 6
// 2290.892 us; speedup vs baseline: 6.1992x; 1.2335x over previous
//
#include <hip/hip_runtime.h>
#include <hip/hip_bf16.h>
#include <stdint.h>
#include <math.h>

typedef __bf16 bf16;
typedef __bf16 bf16x8 __attribute__((ext_vector_type(8)));
typedef float f32x4 __attribute__((ext_vector_type(4)));

// B=8, H=W=128, dim=256, mid=128. fp32 I/O; internal hi/lo bf16 pairs.
// conv = 3-term bf16 (WhAh + WhAl + WlAh) on 16x16x32 MFMA. A (weights)
// loaded global->reg per tap from a fragment-major repack
// [2*tap+s][ci_chunk][co][32ci] (one 1KB coalesced wave-load per fragment,
// L2-resident). B staged once per K-chunk via global_load_lds width=16
// (linear LDS dest + inverse-swizzled per-lane global src, m173 pattern);
// boundary rows / OOB planes zeroed ONCE before the K-loop.
// Verified-dead ends: NW=8 blocks (occupancy collapse x2), 32x32x16 shape
// (same MFMA busy, +conflicts), launch_bounds(512,6) (VGPR cap 40 -> spill).

// ---------------- x: NCHW fp32 -> NHWC hi/lo bf16 (512 ch)
__global__ void k_x_split(const float* __restrict__ in, bf16* __restrict__ out) {
  __shared__ float t[32][33];
  const int b = blockIdx.z;
  const int p0 = blockIdx.x << 5, c0 = blockIdx.y << 5;
  const int tx = threadIdx.x, ty = threadIdx.y;  // block (32,8)
  const float* ib = in + (size_t)b * 256 * 16384;
  bf16* ob = out + (size_t)b * 16384 * 512;
#pragma unroll
  for (int k = 0; k < 32; k += 8)
    t[ty + k][tx] = ib[(size_t)(c0 + ty + k) * 16384 + p0 + tx];
  __syncthreads();
#pragma unroll
  for (int k = 0; k < 32; k += 8) {
    float v = t[tx][ty + k];
    bf16 hv = (bf16)v;
    bf16 lv = (bf16)(v - (float)hv);
    ob[(size_t)(p0 + ty + k) * 512 + c0 + tx] = hv;
    ob[(size_t)(p0 + ty + k) * 512 + 256 + c0 + tx] = lv;
  }
}

// ---------------- weight repack fp32 OIHW -> bf16 [2*tap+s][ci_chunk][co][32ci]
// (s=0 Wh, s=1 Wl). Per-(seg,tap) block is chunk-major so a wave's MFMA A
// fragment (16 co x 32 ci) is 1KB contiguous.
__global__ void k_repack2(const float* __restrict__ src, bf16* __restrict__ dst,
                          int Cout, int Cin, int taps, int coutTotal, int coff) {
  int tid = blockIdx.x * 256 + threadIdx.x;
  int total = Cout * Cin * taps;
  if (tid >= total) return;
  int t = tid % taps;
  int rest = tid / taps;
  int ci = rest % Cin;
  int co = rest / Cin;
  float w = src[tid];
  bf16 wh = (bf16)w;
  bf16 wl = (bf16)(w - (float)wh);
  int nchunk = Cin >> 5;
  size_t segsz = (size_t)coutTotal * Cin;  // = nchunk*coutTotal*32
  size_t base = (((size_t)(2 * t) * nchunk + (ci >> 5)) * coutTotal + coff + co) * 32
                + (ci & 31);
  dst[base] = wh;
  dst[base + segsz] = wl;
}

// ---------------- BN coefficients
__global__ void k_bncoef(const float* __restrict__ g, const float* __restrict__ b,
                         const float* __restrict__ m, const float* __restrict__ v,
                         float* __restrict__ sc, float* __restrict__ sh, int n) {
  int c = blockIdx.x * 256 + threadIdx.x;
  if (c >= n) return;
  float s = g[c] * (1.0f / sqrtf(v[c] + 1e-5f));
  sc[c] = s;
  sh[c] = b[c] - m[c] * s;
}

// ---------------- implicit-GEMM conv, A from global (fragment-major),
// B via global_load_lds into a swizzled slab (swizzle applied on the SOURCE).
// in: hi/lo act tensor (hi at +0, lo at +Cin within rowStride-ch rows).
// out_mode: 0 = hi/lo bf16 NHWC (2*Cout ch), 1 = fp32 NHWC compact,
// 2 = fp32 NCHW. addbuf: hi/lo, stride 2*Cout.
template <int NTAPS>
__global__ __launch_bounds__(256, 3)
void k_conv(const bf16* __restrict__ in, int Cin, int rowStride,
            const bf16* __restrict__ Wr, int Cout,
            const float* __restrict__ scale, const float* __restrict__ shift,
            const bf16* __restrict__ addbuf, int relu,
            int out_mode, void* __restrict__ out) {
  constexpr int R = (NTAPS == 9) ? 3 : 1;
  // plane = hl*R + r; 132 rows/plane: row p holds pos wi=p-1 (p=0,129 zero pad)
  __shared__ bf16 b_slab[2 * R * 132 * 32];
  const int bx = blockIdx.x;
  const int bb = bx & 7, h = (bx >> 3) & 127;   // XCD swizzle: batch == XCD
  const int row = bb * 128 + h;
  const int co_block = blockIdx.y << 7;
  const int tid = threadIdx.x;
  const int lane = tid & 63, wave = tid >> 6;
  const int wm = (wave >> 1) << 6, wn = (wave & 1) << 6;
  const int quad = lane >> 4, l15 = lane & 15;
  const int nchunk = Cin >> 5;
  const size_t segsz = (size_t)Cout * Cin;  // seg stride in repacked weights

  f32x4 acc[4][4];
#pragma unroll
  for (int i = 0; i < 4; ++i)
#pragma unroll
    for (int j = 0; j < 4; ++j)
#pragma unroll
      for (int r = 0; r < 4; ++r) acc[i][j][r] = 0.0f;

  // ---- one-time zeroing: pad rows (p=0,129) of all planes; OOB edge planes
  {
    uint4 z; z.x = z.y = z.z = z.w = 0u;
    for (int u = tid; u < 2 * R * 2 * 4; u += 256) {
      int g = u & 3, e = (u >> 2) & 1, plane = u >> 3;
      bf16* d = &b_slab[((size_t)plane * 132 + (e ? 129 : 0)) * 32 + g * 8];
      *(uint4*)d = z;
    }
    if (R == 3 && (h == 0 || h == 127)) {
      int rr = (h == 0) ? 0 : 2;
      for (int u = tid; u < 2 * 132 * 4; u += 256) {
        int g = u & 3, p = (u >> 2) % 132, hl = (u >> 2) / 132;
        bf16* d = &b_slab[((size_t)(hl * R + rr) * 132 + p) * 32 + g * 8];
        *(uint4*)d = z;
      }
    }
  }

  for (int cb = 0; cb < Cin; cb += 32) {
    // ---- async stage rows 1..128 of each in-bounds plane (8 x 1KB per plane).
    // LDS linear; swizzle folded into the per-lane GLOBAL address:
    // slot s of row p holds global granule s ^ ((p>>1)&3).
    for (int u = wave; u < 2 * R * 8; u += 4) {
      int plane = u >> 3, sub = u & 7;
      int hl, rr;
      if (R == 3) { hl = plane >= 3; rr = plane - (hl ? 3 : 0); }
      else        { hl = plane; rr = 0; }
      int hi = h + rr - (R == 3 ? 1 : 0);
      if ((unsigned)hi < 128u) {
        int p = 1 + sub * 16 + (lane >> 2);             // row this lane covers
        int gsw = (lane & 3) ^ ((p >> 1) & 3);          // source granule
        const bf16* src = in + (size_t)((bb * 128 + hi) * 128 + (p - 1)) * rowStride
                          + (size_t)hl * Cin + cb + gsw * 8;
        bf16* dst = &b_slab[(size_t)(plane * 132 + 1 + sub * 16) * 32];
        __builtin_amdgcn_global_load_lds(
            (const __attribute__((address_space(1))) uint32_t*)src,
            (__attribute__((address_space(3))) uint32_t*)dst, 16, 0, 0);
      }
    }
    __syncthreads();
#pragma unroll
    for (int tap = 0; tap < NTAPS; ++tap) {
      const int rr = (R == 3) ? (tap / 3) : 0;        // slab row
      const int wc = (R == 3) ? (tap % 3) : 1;        // dw+1 column offset
      const int bH = rr * 132;
      const int bL = (R + rr) * 132;
      const int p0 = wn + l15 + wc;                   // j=0 position (j adds 16)
      const int sw8 = (((p0 >> 1) & 3) ^ quad) << 3;  // invariant across j
      // ---- A fragments straight from L2; fragment-major layout:
      // lane addr = l15*64B + quad*16B -> one coalesced 1KB load per fragment
      const bf16* Ah = Wr + (((size_t)(2 * tap) * nchunk + (cb >> 5)) * Cout
                             + co_block + wm + l15) * 32 + quad * 8;
      const bf16* Al = Ah + segsz;
      bf16x8 afH[4], afL[4], bfH[4], bfL[4];
#pragma unroll
      for (int i = 0; i < 4; ++i) {
        afH[i] = *(const bf16x8*)(Ah + (size_t)i * 16 * 32);
        afL[i] = *(const bf16x8*)(Al + (size_t)i * 16 * 32);
      }
#pragma unroll
      for (int j = 0; j < 4; ++j) {
        const int p_idx = p0 + j * 16;
        bfH[j] = *(const bf16x8*)&b_slab[(size_t)(bH + p_idx) * 32 + sw8];
        bfL[j] = *(const bf16x8*)&b_slab[(size_t)(bL + p_idx) * 32 + sw8];
      }
#pragma unroll
      for (int i = 0; i < 4; ++i)
#pragma unroll
        for (int j = 0; j < 4; ++j) {
          acc[i][j] = __builtin_amdgcn_mfma_f32_16x16x32_bf16(afH[i], bfH[j], acc[i][j], 0, 0, 0);
          acc[i][j] = __builtin_amdgcn_mfma_f32_16x16x32_bf16(afH[i], bfL[j], acc[i][j], 0, 0, 0);
          acc[i][j] = __builtin_amdgcn_mfma_f32_16x16x32_bf16(afL[i], bfH[j], acc[i][j], 0, 0, 0);
        }
    }
    __syncthreads();  // slab reads done before next chunk's restage
  }

  // epilogue: D row(m=cout)=quad*4+reg, col(n=pos)=lane&15
#pragma unroll
  for (int i = 0; i < 4; ++i) {
    const int co = co_block + wm + i * 16 + (quad << 2);
#pragma unroll
    for (int j = 0; j < 4; ++j) {
      const int pos = wn + j * 16 + l15;
      float v[4];
#pragma unroll
      for (int r = 0; r < 4; ++r) v[r] = acc[i][j][r];
      if (scale) {
#pragma unroll
        for (int r = 0; r < 4; ++r) v[r] = v[r] * scale[co + r] + shift[co + r];
      }
      if (addbuf) {
        const bf16* ah = addbuf + (size_t)(row * 128 + pos) * (2 * Cout) + co;
        const bf16* al = ah + Cout;
#pragma unroll
        for (int r = 0; r < 4; ++r) v[r] += (float)ah[r] + (float)al[r];
      }
      if (relu) {
#pragma unroll
        for (int r = 0; r < 4; ++r) v[r] = fmaxf(v[r], 0.0f);
      }
      if (out_mode == 0) {
        bf16* ob = (bf16*)out;
        union { bf16 hv[4]; uint2 u; } ph, pl;
#pragma unroll
        for (int r = 0; r < 4; ++r) {
          ph.hv[r] = (bf16)v[r];
          pl.hv[r] = (bf16)(v[r] - (float)ph.hv[r]);
        }
        const size_t base = (size_t)(row * 128 + pos) * (2 * Cout);
        *(uint2*)&ob[base + co] = ph.u;
        *(uint2*)&ob[base + Cout + co] = pl.u;
      } else if (out_mode == 1) {
        float* of = (float*)out;
        float4 pk = make_float4(v[0], v[1], v[2], v[3]);
        *(float4*)&of[(size_t)(row * 128 + pos) * Cout + co] = pk;
      } else {
        float* of = (float*)out;
#pragma unroll
        for (int r = 0; r < 4; ++r)
          of[((size_t)(bb * Cout + co + r) * 128 + h) * 128 + pos] = v[r];
      }
    }
  }
}

// ---------------- pools (fp32 reconstruct, scan, re-split), in-place
// y: 512ch rows [lookH 0:128 | pH 128:256 | lookL 256:384 | pL 384:512]
__global__ void k_pool_s1(bf16* __restrict__ y) {  // left_pool: scan w
  int tid = blockIdx.x * 256 + threadIdx.x;
  int c = tid & 127, h = (tid >> 7) & 127, b = tid >> 14;
  bf16* base = y + (size_t)((b * 128 + h) * 128) * 512;
  float run = -INFINITY;
  for (int w = 127; w >= 0; --w) {
    bf16* p = base + (size_t)w * 512;
    float look = (float)p[c] + (float)p[256 + c];
    float padd = (float)p[128 + c] + (float)p[384 + c];
    run = fmaxf(run, look);
    float sum = run + padd;
    bf16 hv = (bf16)sum;
    p[c] = hv;
    p[128 + c] = (bf16)(sum - (float)hv);
  }
}
__global__ void k_pool_s2(bf16* __restrict__ y) {  // top_pool: scan h
  int tid = blockIdx.x * 256 + threadIdx.x;
  int c = tid & 127, w = (tid >> 7) & 127, b = tid >> 14;
  bf16* base = y + ((size_t)b * 16384 + w) * 512;
  float run = -INFINITY;
  for (int hh = 127; hh >= 0; --hh) {
    bf16* p = base + (size_t)hh * 65536;
    float look = (float)p[c] + (float)p[256 + c];
    float padd = (float)p[128 + c] + (float)p[384 + c];
    run = fmaxf(run, look);
    float sum = run + padd;
    bf16 hv = (bf16)sum;
    p[c] = hv;
    p[128 + c] = (bf16)(sum - (float)hv);
  }
}
__global__ void k_tpool_f(float* __restrict__ buf) {  // in-place top_pool fp32
  int tid = blockIdx.x * 256 + threadIdx.x;
  int c = tid & 127, w = (tid >> 7) & 127, b = tid >> 14;
  float* p = buf + ((size_t)b * 16384 + w) * 128 + c;
  float run = -INFINITY;
  for (int hh = 127; hh >= 0; --hh) {
    run = fmaxf(run, p[(size_t)hh * 16384]);
    p[(size_t)hh * 16384] = run;
  }
}
__global__ void k_lpool_add_f(const float* __restrict__ in, const float* __restrict__ addb,
                              bf16* __restrict__ out) {
  int tid = blockIdx.x * 256 + threadIdx.x;
  int c = tid & 127, h = (tid >> 7) & 127, b = tid >> 14;
  const float* p = in + (size_t)((b * 128 + h) * 128) * 128 + c;
  const float* a = addb + (size_t)((b * 128 + h) * 128) * 128 + c;
  bf16* o = out + (size_t)((b * 128 + h) * 128) * 256;
  float run = -INFINITY;
  for (int w = 127; w >= 0; --w) {
    run = fmaxf(run, p[(size_t)w * 128]);
    float sum = run + a[(size_t)w * 128];
    bf16 hv = (bf16)sum;
    o[(size_t)w * 256 + c] = hv;
    o[(size_t)w * 256 + 128 + c] = (bf16)(sum - (float)hv);
  }
}

extern "C" void kernel_launch(void* const* d_in, const int* in_sizes, int n_in,
                              void* d_out, int out_size, void* d_ws, size_t ws_size,
                              hipStream_t stream) {
  (void)in_sizes; (void)n_in; (void)out_size; (void)ws_size;
#define INF(i) ((const float*)d_in[i])
  char* ws = (char*)d_ws;
  const size_t MB = 1 << 20;
  // weights [0, ~9.75MB): [2*tap+s][ci_chunk][co][32]
  bf16* wrA  = (bf16*)(ws + 0);          // 18*256*256
  bf16* wrB  = (bf16*)(ws + 2359296);
  bf16* wrp1 = (bf16*)(ws + 4718592);    // 18*128*128
  bf16* wrp2 = (bf16*)(ws + 5308416);
  bf16* wrpc = (bf16*)(ws + 5898240);    // 18*256*128
  bf16* wrc1 = (bf16*)(ws + 7077888);    // 2*256*256
  bf16* wrc2 = (bf16*)(ws + 7340032);    // 18*256*256
  float* scA  = (float*)(ws + 9699328);
  float* shA  = (float*)(ws + 9703424);
  float* scB  = (float*)(ws + 9707520);
  float* shB  = (float*)(ws + 9711616);
  float* scp  = (float*)(ws + 9715712);
  float* shp  = (float*)(ws + 9719808);
  float* scb  = (float*)(ws + 9723904);
  float* shb  = (float*)(ws + 9728000);
  float* scc2 = (float*)(ws + 9732096);
  float* shc2 = (float*)(ws + 9736192);
  // activations (ws use <= 330 MB; d_out doubles as 128 MB scratch)
  bf16*  x_hl  = (bf16*)(ws + 10 * MB);    // 128 MB, live thru step 8
  bf16*  bnrel = (bf16*)(ws + 138 * MB);   // 128 MB: bn1 -> relu1 in-place
  float* p1lk  = (float*)(ws + 266 * MB);  // 64 MB fp32
  float* p2lk  = (float*)(ws + 10 * MB);   // 64 MB fp32 over dead x_hl
  bf16*  psum  = (bf16*)(ws + 74 * MB);    // 64 MB hi/lo compact 256ch
  bf16*  yscr  = (bf16*)d_out;             // 128 MB scratch: yA/s1 then yB/s2

  // 1) x -> NHWC hi/lo
  k_x_split<<<dim3(512, 8, 8), dim3(32, 8), 0, stream>>>(INF(0), x_hl);

  // 2) weight repacks (Wh/Wl segments)
  k_repack2<<<1152, 256, 0, stream>>>(INF(1),  wrA,  128, 256, 9, 256, 0);
  k_repack2<<<1152, 256, 0, stream>>>(INF(6),  wrA,  128, 256, 9, 256, 128);
  k_repack2<<<1152, 256, 0, stream>>>(INF(11), wrB,  128, 256, 9, 256, 0);
  k_repack2<<<1152, 256, 0, stream>>>(INF(16), wrB,  128, 256, 9, 256, 128);
  k_repack2<<<576,  256, 0, stream>>>(INF(21), wrp1, 128, 128, 9, 128, 0);
  k_repack2<<<576,  256, 0, stream>>>(INF(22), wrp2, 128, 128, 9, 128, 0);
  k_repack2<<<1152, 256, 0, stream>>>(INF(23), wrpc, 256, 128, 9, 256, 0);
  k_repack2<<<256,  256, 0, stream>>>(INF(28), wrc1, 256, 256, 1, 256, 0);
  k_repack2<<<2304, 256, 0, stream>>>(INF(33), wrc2, 256, 256, 9, 256, 0);

  // 3) BN coefficients
  k_bncoef<<<1, 256, 0, stream>>>(INF(2),  INF(3),  INF(4),  INF(5),  scA,       shA,       128);
  k_bncoef<<<1, 256, 0, stream>>>(INF(7),  INF(8),  INF(9),  INF(10), scA + 128, shA + 128, 128);
  k_bncoef<<<1, 256, 0, stream>>>(INF(12), INF(13), INF(14), INF(15), scB,       shB,       128);
  k_bncoef<<<1, 256, 0, stream>>>(INF(17), INF(18), INF(19), INF(20), scB + 128, shB + 128, 128);
  k_bncoef<<<1, 256, 0, stream>>>(INF(24), INF(25), INF(26), INF(27), scp, shp, 256);
  k_bncoef<<<1, 256, 0, stream>>>(INF(29), INF(30), INF(31), INF(32), scb, shb, 256);
  k_bncoef<<<1, 256, 0, stream>>>(INF(34), INF(35), INF(36), INF(37), scc2, shc2, 256);

  // 4) bn1 = BN(conv1x1(x)) -> bnrel (hi/lo)
  k_conv<1><<<dim3(1024, 2), 256, 0, stream>>>(x_hl, 256, 512, wrc1, 256, scb, shb, nullptr, 0, 0, bnrel);
  // 5) yA = [look_conv1 | p1_conv1] (BN+ReLU) -> d_out scratch
  k_conv<9><<<dim3(1024, 2), 256, 0, stream>>>(x_hl, 256, 512, wrA, 256, scA, shA, nullptr, 1, 0, yscr);
  // 6) s1 = left_pool(look1) + p1_conv1 (in-place, ch [0:256))
  k_pool_s1<<<512, 256, 0, stream>>>(yscr);
  // 7) p1_look = conv(s1, p1lc) -> fp32
  k_conv<9><<<dim3(1024, 1), 256, 0, stream>>>(yscr, 128, 512, wrp1, 128, nullptr, nullptr, nullptr, 0, 1, p1lk);
  // 8) yB = [look_conv2 | p2_conv1] -> d_out scratch (x dead after)
  k_conv<9><<<dim3(1024, 2), 256, 0, stream>>>(x_hl, 256, 512, wrB, 256, scB, shB, nullptr, 1, 0, yscr);
  // 9) s2 = top_pool(look2) + p2_conv1 (in-place)
  k_pool_s2<<<512, 256, 0, stream>>>(yscr);
  // 10) p2_look = conv(s2, p2lc) -> fp32 (over dead x_hl)
  k_conv<9><<<dim3(1024, 1), 256, 0, stream>>>(yscr, 128, 512, wrp2, 128, nullptr, nullptr, nullptr, 0, 1, p2lk);
  // 11) ptmp = top_pool(p1_look) in-place
  k_tpool_f<<<512, 256, 0, stream>>>(p1lk);
  // 12) psum = left_pool(p2_look) + ptmp -> hi/lo compact
  k_lpool_add_f<<<512, 256, 0, stream>>>(p2lk, p1lk, psum);
  // 13) relu1 = relu(BN(conv(psum, pconv1)) + bn1) in-place over bn1
  k_conv<9><<<dim3(1024, 2), 256, 0, stream>>>(psum, 128, 256, wrpc, 256, scp, shp, bnrel, 1, 0, bnrel);
  // 14) out = relu(BN(conv(relu1, c2))) -> NCHW fp32 d_out
  k_conv<9><<<dim3(1024, 2), 256, 0, stream>>>(bnrel, 256, 512, wrc2, 256, scc2, shc2, nullptr, 1, 2, (float*)d_out);
#undef INF
}